// Round 2
// baseline (178.691 us; speedup 1.0000x reference)
//
#include <hip/hip_runtime.h>
#include <stdint.h>

#define THREADS 256
#define TM 128
#define TN 128
#define BK 64
#define MAXTILES 40
#define NE 8
#define BB 4
#define SS 512
#define KK 2
#define II 1024
#define DD 2048
#define NTOK (BB * SS)         // 2048
#define NASSIGN (BB * KK * SS) // 4096
#define KSPAN 1024             // K handled per block (gemm2 split-K)

typedef unsigned short u16;
typedef __attribute__((ext_vector_type(8))) __bf16 bf16x8;
typedef __attribute__((ext_vector_type(4))) float f32x4;

__device__ __forceinline__ u16 f32_to_bf16(float f) {
    unsigned int u = __builtin_bit_cast(unsigned int, f);
    unsigned int r = u + 0x7FFFu + ((u >> 16) & 1u);
    return (u16)(r >> 16);
}

__device__ __forceinline__ void gload16(const void* g, void* l) {
    __builtin_amdgcn_global_load_lds(
        (const __attribute__((address_space(1))) unsigned int*)g,
        (__attribute__((address_space(3))) unsigned int*)l, 16, 0, 0);
}

// ---------------- setup: bucket assignments by expert ----------------
__global__ void setup_kernel(const void* __restrict__ ens_raw,
                             const float* __restrict__ weights,
                             int* __restrict__ meta,
                             int* __restrict__ tok,
                             float* __restrict__ wgt) {
    __shared__ int s_cnt[NE];
    __shared__ int s_cur[NE];
    __shared__ int s_flag;
    const int t = threadIdx.x;
    if (t < NE) s_cnt[t] = 0;
    if (t == 0) s_flag = 0;
    __syncthreads();

    // dtype detect: int64 ensembles (vals 0..7) -> all odd 32-bit words zero
    const unsigned int* w32 = (const unsigned int*)ens_raw;
    unsigned int f = 0;
    for (int i = t; i < NASSIGN / 2; i += THREADS) f |= w32[2 * i + 1];
    if (f) atomicOr(&s_flag, 1);
    __syncthreads();
    const bool is32 = (s_flag != 0);
    const int* e32 = (const int*)ens_raw;
    const long long* e64 = (const long long*)ens_raw;

    for (int a = t; a < NASSIGN; a += THREADS) {
        int e = is32 ? e32[a] : (int)e64[a];
        atomicAdd(&s_cnt[e & 7], 1);
    }
    __syncthreads();

    if (t == 0) {
        int pb = 0, nt = 0;
        for (int e = 0; e < NE; e++) {
            int c = s_cnt[e];
            meta[8 + e] = c;
            meta[16 + e] = pb;
            s_cur[e] = pb;
            int ntile = (c + TM - 1) / TM;
            for (int i = 0; i < ntile; i++) {
                meta[32 + nt] = e;           // tile -> expert
                meta[80 + nt] = pb + i * TM; // tile -> slot base
                meta[128 + nt] = pb + c;     // tile -> real end
                nt++;
            }
            pb += ntile * TM;
        }
        meta[0] = nt;
        meta[1] = pb;
    }
    __syncthreads();

    for (int a = t; a < NASSIGN; a += THREADS) {
        int e = is32 ? e32[a] : (int)e64[a];
        e &= 7;
        int slot = atomicAdd(&s_cur[e], 1);
        int b = a >> 10;      // a / (K*S)
        int s = a & (SS - 1); // a % S
        tok[slot] = b * SS + s;
        wgt[slot] = weights[a];
    }
    __syncthreads();

    // pad fill
    for (int e = 0; e < NE; e++) {
        int st = meta[16 + e] + meta[8 + e];
        int en = (e < NE - 1) ? meta[16 + e + 1] : meta[1];
        for (int i = st + t; i < en; i += THREADS) {
            tok[i] = 0;
            wgt[i] = 0.f;
        }
    }
}

// ---------------- fused f32 -> bf16 conversion (all 3 arrays) ----------------
__global__ void convert_all(const float* __restrict__ x,
                            const float* __restrict__ pin,
                            const float* __restrict__ pout,
                            u16* __restrict__ xb,
                            u16* __restrict__ pb1,
                            u16* __restrict__ pb2) {
    const int n1 = NTOK * II / 8;
    const int n2 = NE * DD * II / 8;
    const int total = n1 + 2 * n2;
    for (int i = blockIdx.x * blockDim.x + threadIdx.x; i < total;
         i += gridDim.x * blockDim.x) {
        const float* s;
        u16* d;
        int k;
        if (i < n1) { s = x; d = xb; k = i; }
        else if (i < n1 + n2) { s = pin; d = pb1; k = i - n1; }
        else { s = pout; d = pb2; k = i - n1 - n2; }
        const float4* s4 = (const float4*)s;
        float4 a = s4[2 * (size_t)k];
        float4 b = s4[2 * (size_t)k + 1];
        union { u16 u[8]; uint4 v; } o;
        o.u[0] = f32_to_bf16(a.x); o.u[1] = f32_to_bf16(a.y);
        o.u[2] = f32_to_bf16(a.z); o.u[3] = f32_to_bf16(a.w);
        o.u[4] = f32_to_bf16(b.x); o.u[5] = f32_to_bf16(b.y);
        o.u[6] = f32_to_bf16(b.z); o.u[7] = f32_to_bf16(b.w);
        *(uint4*)(d + 8 * (size_t)k) = o.v;
    }
}

// ---------------- grouped GEMM, 2-phase double-buffered ----------------
// MODE 0: h[slot] = relu(x[tok[slot]] @ proj_in[e]^T)      (M x 1024) -> (M x 2048)
// MODE 1: out[tok[slot]] += wgt * (h[slot] @ proj_out[e]^T) (M x 2048) -> (M x 1024)
//         K=2048 split across blockIdx.z (2 x KSPAN)
template <int MODE>
__global__ __launch_bounds__(THREADS)
void gemm_kernel(const u16* __restrict__ Abase,
                 const u16* __restrict__ Bbase,
                 const int* __restrict__ meta,
                 const int* __restrict__ tok,
                 const float* __restrict__ wgt,
                 u16* __restrict__ hdst,
                 float* __restrict__ outdst) {
    constexpr int Kdim = (MODE == 0) ? II : DD; // row stride in K
    constexpr int NT = KSPAN / BK;              // 16 K-steps per block
    const int tile = blockIdx.x;
    if (tile >= meta[0]) return;
    const int e = meta[32 + tile];
    const int sbase = meta[80 + tile];
    const int rend = meta[128 + tile];
    const int colbase = blockIdx.y * TN;
    const int kbase = blockIdx.z * KSPAN;

    __shared__ u16 ldsA[2][TM * BK];
    __shared__ u16 ldsB[2][TN * BK];

    const int lane = threadIdx.x & 63;
    const int wv = threadIdx.x >> 6;

    const u16* Bp = Bbase + (size_t)e * (size_t)(DD * II) + (size_t)colbase * Kdim;

    // staging: 16B chunk c -> LDS byte 16c (linear dest); source pre-swizzled
    int aoff[4], boff[4], ldst[4];
#pragma unroll
    for (int j = 0; j < 4; j++) {
        int c = (j * 4 + wv) * 64 + lane;
        int row = c >> 3;
        int s = (c & 7) ^ (row & 7); // inverse-swizzled source slot
        ldst[j] = (j * 4 + wv) * 512;
        if (MODE == 0) {
            aoff[j] = tok[sbase + row] * II + s * 8 + kbase;
        } else {
            aoff[j] = (sbase + row) * DD + s * 8 + kbase;
        }
        boff[j] = row * Kdim + s * 8 + kbase;
    }

    f32x4 acc[4][4];
#pragma unroll
    for (int mi = 0; mi < 4; mi++)
#pragma unroll
        for (int ni = 0; ni < 4; ni++)
            acc[mi][ni] = (f32x4){0.f, 0.f, 0.f, 0.f};

    const int wr = (wv >> 1) * 64;
    const int wc = (wv & 1) * 64;

    // prologue: stage tile 0 into buf 0
#pragma unroll
    for (int j = 0; j < 4; j++) gload16(Abase + aoff[j], &ldsA[0][ldst[j]]);
#pragma unroll
    for (int j = 0; j < 4; j++) gload16(Bp + boff[j], &ldsB[0][ldst[j]]);
    __syncthreads();

    for (int ks = 0; ks < NT; ks++) {
        const int buf = ks & 1;
        // stage next tile into the other buffer (overlaps with compute below)
        if (ks + 1 < NT) {
            const int kof = (ks + 1) * BK;
#pragma unroll
            for (int j = 0; j < 4; j++)
                gload16(Abase + aoff[j] + kof, &ldsA[buf ^ 1][ldst[j]]);
#pragma unroll
            for (int j = 0; j < 4; j++)
                gload16(Bp + boff[j] + kof, &ldsB[buf ^ 1][ldst[j]]);
        }
        // compute current buffer
#pragma unroll
        for (int kk = 0; kk < 2; kk++) {
            bf16x8 af[4], bfr[4];
#pragma unroll
            for (int mi = 0; mi < 4; mi++) {
                int row = wr + mi * 16 + (lane & 15);
                int slot = (kk * 4 + (lane >> 4)) ^ (row & 7);
                af[mi] = *(const bf16x8*)&ldsA[buf][row * BK + slot * 8];
            }
#pragma unroll
            for (int ni = 0; ni < 4; ni++) {
                int row = wc + ni * 16 + (lane & 15);
                int slot = (kk * 4 + (lane >> 4)) ^ (row & 7);
                bfr[ni] = *(const bf16x8*)&ldsB[buf][row * BK + slot * 8];
            }
#pragma unroll
            for (int mi = 0; mi < 4; mi++)
#pragma unroll
                for (int ni = 0; ni < 4; ni++)
                    acc[mi][ni] = __builtin_amdgcn_mfma_f32_16x16x32_bf16(
                        af[mi], bfr[ni], acc[mi][ni], 0, 0, 0);
        }
        __syncthreads(); // drains vmcnt (next-tile stage) + lds reads
    }

    if (MODE == 0) {
#pragma unroll
        for (int mi = 0; mi < 4; mi++) {
#pragma unroll
            for (int r = 0; r < 4; r++) {
                int row = wr + mi * 16 + (lane >> 4) * 4 + r;
                size_t rowoff = (size_t)(sbase + row) * DD;
#pragma unroll
                for (int ni = 0; ni < 4; ni++) {
                    int col = colbase + wc + ni * 16 + (lane & 15);
                    float v = acc[mi][ni][r];
                    v = v > 0.f ? v : 0.f;
                    hdst[rowoff + col] = f32_to_bf16(v);
                }
            }
        }
    } else {
#pragma unroll
        for (int mi = 0; mi < 4; mi++) {
#pragma unroll
            for (int r = 0; r < 4; r++) {
                int row = wr + mi * 16 + (lane >> 4) * 4 + r;
                int slot = sbase + row;
                if (slot < rend) { // skip padding rows
                    float w = wgt[slot];
                    size_t obase = (size_t)tok[slot] * II;
#pragma unroll
                    for (int ni = 0; ni < 4; ni++) {
                        int col = colbase + wc + ni * 16 + (lane & 15);
                        atomicAdd(&outdst[obase + col], acc[mi][ni][r] * w);
                    }
                }
            }
        }
    }
}

// ---------------- launch ----------------
extern "C" void kernel_launch(void* const* d_in, const int* in_sizes, int n_in,
                              void* d_out, int out_size, void* d_ws, size_t ws_size,
                              hipStream_t stream) {
    const float* x = (const float*)d_in[0];
    const float* weights = (const float*)d_in[1];
    const void* ens = d_in[2];
    const float* pin = (const float*)d_in[3];
    const float* pout = (const float*)d_in[4];
    float* out = (float*)d_out;

    char* ws = (char*)d_ws;
    int*   meta    = (int*)(ws);            // 1 KB
    int*   tok     = (int*)(ws + 1024);     // 20 KB
    float* wgt     = (float*)(ws + 21504);  // 20 KB   -> 41984
    u16*   x_bf    = (u16*)(ws + 41984);    // 4 MB    -> 4236288
    u16*   pin_bf  = (u16*)(ws + 4236288);  // 33.5 MB -> 37790720
    u16*   pout_bf = (u16*)(ws + 37790720); // 33.5 MB -> 71345152
    u16*   h       = (u16*)(ws + 71345152); // 21 MB   -> 92316672 total

    setup_kernel<<<dim3(1), dim3(THREADS), 0, stream>>>(ens, weights, meta, tok, wgt);

    convert_all<<<dim3(2048), dim3(256), 0, stream>>>(x, pin, pout, x_bf, pin_bf, pout_bf);

    gemm_kernel<0><<<dim3(MAXTILES, DD / TN, 1), dim3(THREADS), 0, stream>>>(
        x_bf, pin_bf, meta, tok, wgt, h, nullptr);

    hipMemsetAsync(d_out, 0, (size_t)out_size * sizeof(float), stream);

    gemm_kernel<1><<<dim3(MAXTILES, II / TN, 2), dim3(THREADS), 0, stream>>>(
        h, pout_bf, meta, tok, wgt, nullptr, out);
}

// Round 3
// 143.856 us; speedup vs baseline: 1.2422x; 1.2422x over previous
//
#include <hip/hip_runtime.h>
#include <stdint.h>

#define THREADS 256
#define TM 128
#define TN 128
#define BK 64
#define MAXTILES 40
#define NE 8
#define BB 4
#define SS 512
#define KK 2
#define II 1024
#define DD 2048
#define NTOK (BB * SS)         // 2048
#define NASSIGN (BB * KK * SS) // 4096

typedef unsigned short u16;
typedef __attribute__((ext_vector_type(8))) __bf16 bf16x8;
typedef __attribute__((ext_vector_type(4))) float f32x4;

__device__ __forceinline__ u16 f32_to_bf16(float f) {
    unsigned int u = __builtin_bit_cast(unsigned int, f);
    unsigned int r = u + 0x7FFFu + ((u >> 16) & 1u);
    return (u16)(r >> 16);
}

__device__ __forceinline__ void gload16(const void* g, void* l) {
    __builtin_amdgcn_global_load_lds(
        (const __attribute__((address_space(1))) unsigned int*)g,
        (__attribute__((address_space(3))) unsigned int*)l, 16, 0, 0);
}

// ---------------- setup: bucket assignments by expert ----------------
__global__ void setup_kernel(const void* __restrict__ ens_raw,
                             const float* __restrict__ weights,
                             int* __restrict__ meta,
                             int* __restrict__ tok,
                             float* __restrict__ wgt) {
    __shared__ int s_cnt[NE];
    __shared__ int s_cur[NE];
    __shared__ int s_flag;
    const int t = threadIdx.x;
    if (t < NE) s_cnt[t] = 0;
    if (t == 0) s_flag = 0;
    __syncthreads();

    // dtype detect: int64 ensembles (vals 0..7) -> all odd 32-bit words zero
    const unsigned int* w32 = (const unsigned int*)ens_raw;
    unsigned int f = 0;
    for (int i = t; i < NASSIGN / 2; i += THREADS) f |= w32[2 * i + 1];
    if (f) atomicOr(&s_flag, 1);
    __syncthreads();
    const bool is32 = (s_flag != 0);
    const int* e32 = (const int*)ens_raw;
    const long long* e64 = (const long long*)ens_raw;

    for (int a = t; a < NASSIGN; a += THREADS) {
        int e = is32 ? e32[a] : (int)e64[a];
        atomicAdd(&s_cnt[e & 7], 1);
    }
    __syncthreads();

    if (t == 0) {
        int pb = 0, nt = 0;
        for (int e = 0; e < NE; e++) {
            int c = s_cnt[e];
            meta[8 + e] = c;
            meta[16 + e] = pb;
            s_cur[e] = pb;
            int ntile = (c + TM - 1) / TM;
            for (int i = 0; i < ntile; i++) {
                meta[32 + nt] = e;           // tile -> expert
                meta[80 + nt] = pb + i * TM; // tile -> slot base
                meta[128 + nt] = pb + c;     // tile -> real end
                nt++;
            }
            pb += ntile * TM;
        }
        meta[0] = nt;
        meta[1] = pb;
    }
    __syncthreads();

    for (int a = t; a < NASSIGN; a += THREADS) {
        int e = is32 ? e32[a] : (int)e64[a];
        e &= 7;
        int slot = atomicAdd(&s_cur[e], 1);
        int b = a >> 10;      // a / (K*S)
        int s = a & (SS - 1); // a % S
        tok[slot] = b * SS + s;
        wgt[slot] = weights[a];
    }
    __syncthreads();

    // pad fill
    for (int e = 0; e < NE; e++) {
        int st = meta[16 + e] + meta[8 + e];
        int en = (e < NE - 1) ? meta[16 + e + 1] : meta[1];
        for (int i = st + t; i < en; i += THREADS) {
            tok[i] = 0;
            wgt[i] = 0.f;
        }
    }
}

// ---------------- fused f32 -> bf16 conversion (all 3 arrays) ----------------
__global__ void convert_all(const float* __restrict__ x,
                            const float* __restrict__ pin,
                            const float* __restrict__ pout,
                            u16* __restrict__ xb,
                            u16* __restrict__ pb1,
                            u16* __restrict__ pb2) {
    const int n1 = NTOK * II / 8;
    const int n2 = NE * DD * II / 8;
    const int total = n1 + 2 * n2;
    for (int i = blockIdx.x * blockDim.x + threadIdx.x; i < total;
         i += gridDim.x * blockDim.x) {
        const float* s;
        u16* d;
        int k;
        if (i < n1) { s = x; d = xb; k = i; }
        else if (i < n1 + n2) { s = pin; d = pb1; k = i - n1; }
        else { s = pout; d = pb2; k = i - n1 - n2; }
        const float4* s4 = (const float4*)s;
        float4 a = s4[2 * (size_t)k];
        float4 b = s4[2 * (size_t)k + 1];
        union { u16 u[8]; uint4 v; } o;
        o.u[0] = f32_to_bf16(a.x); o.u[1] = f32_to_bf16(a.y);
        o.u[2] = f32_to_bf16(a.z); o.u[3] = f32_to_bf16(a.w);
        o.u[4] = f32_to_bf16(b.x); o.u[5] = f32_to_bf16(b.y);
        o.u[6] = f32_to_bf16(b.z); o.u[7] = f32_to_bf16(b.w);
        *(uint4*)(d + 8 * (size_t)k) = o.v;
    }
}

// ---------------- grouped GEMM (R1 structure + XCD-chunked block swizzle) --
// MODE 0: h[slot] = relu(x[tok[slot]] @ proj_in[e]^T)      (M x 1024) -> (M x 2048)
//         grid 640 = 8 XCD-chunks of (10 tiles x 8 cols)
// MODE 1: out[tok[slot]] += wgt * (h[slot] @ proj_out[e]^T) (M x 2048) -> (M x 1024)
//         grid 320 = 8 XCD-chunks of (5 tiles x 8 cols)
template <int MODE>
__global__ __launch_bounds__(THREADS)
void gemm_kernel(const u16* __restrict__ Abase,
                 const u16* __restrict__ Bbase,
                 const int* __restrict__ meta,
                 const int* __restrict__ tok,
                 const float* __restrict__ wgt,
                 u16* __restrict__ hdst,
                 float* __restrict__ outdst) {
    constexpr int Kdim = (MODE == 0) ? II : DD;

    // XCD-aware 2-D chunk decode: XCD = lid & 7 (round-robin dispatch heuristic)
    const int lid = blockIdx.x;
    const int g = lid & 7;
    const int i = lid >> 3;
    int tile, colt;
    if (MODE == 0) {
        // 8 chunks arranged 4 (tile) x 2 (col); each chunk 10 tiles x 8 cols
        const int gy = g >> 1, gx = g & 1;
        tile = gy * 10 + (i % 10);
        colt = gx * 8 + (i / 10);
    } else {
        // 8 chunks of 5 tiles x 8 cols
        tile = g * 5 + (i % 5);
        colt = i / 5;
    }
    if (tile >= meta[0]) return;

    const int e = meta[32 + tile];
    const int sbase = meta[80 + tile];
    const int rend = meta[128 + tile];
    const int colbase = colt * TN;

    __shared__ u16 ldsA[TM * BK];
    __shared__ u16 ldsB[TN * BK];

    const int lane = threadIdx.x & 63;
    const int wv = threadIdx.x >> 6;

    const u16* Bp = Bbase + (size_t)e * (size_t)(DD * II) + (size_t)colbase * Kdim;

    // staging: 16B chunk c -> LDS byte 16c (linear dest); source pre-swizzled
    int aoff[4], boff[4], ldst[4];
#pragma unroll
    for (int j = 0; j < 4; j++) {
        int c = (j * 4 + wv) * 64 + lane;
        int row = c >> 3;
        int s = (c & 7) ^ (row & 7); // inverse-swizzled source slot
        ldst[j] = (j * 4 + wv) * 512;
        if (MODE == 0) {
            aoff[j] = tok[sbase + row] * II + s * 8;
        } else {
            aoff[j] = (sbase + row) * DD + s * 8;
        }
        boff[j] = row * Kdim + s * 8;
    }

    f32x4 acc[4][4];
#pragma unroll
    for (int mi = 0; mi < 4; mi++)
#pragma unroll
        for (int ni = 0; ni < 4; ni++)
            acc[mi][ni] = (f32x4){0.f, 0.f, 0.f, 0.f};

    const int wr = (wv >> 1) * 64;
    const int wc = (wv & 1) * 64;

    for (int ks = 0; ks < Kdim / BK; ks++) {
        const int kof = ks * BK;
#pragma unroll
        for (int j = 0; j < 4; j++)
            gload16(Abase + aoff[j] + kof, &ldsA[ldst[j]]);
#pragma unroll
        for (int j = 0; j < 4; j++)
            gload16(Bp + boff[j] + kof, &ldsB[ldst[j]]);
        __syncthreads(); // drains vmcnt before LDS reads

#pragma unroll
        for (int kk = 0; kk < 2; kk++) {
            bf16x8 af[4], bfr[4];
#pragma unroll
            for (int mi = 0; mi < 4; mi++) {
                int row = wr + mi * 16 + (lane & 15);
                int slot = (kk * 4 + (lane >> 4)) ^ (row & 7);
                af[mi] = *(const bf16x8*)&ldsA[row * BK + slot * 8];
            }
#pragma unroll
            for (int ni = 0; ni < 4; ni++) {
                int row = wc + ni * 16 + (lane & 15);
                int slot = (kk * 4 + (lane >> 4)) ^ (row & 7);
                bfr[ni] = *(const bf16x8*)&ldsB[row * BK + slot * 8];
            }
#pragma unroll
            for (int mi = 0; mi < 4; mi++)
#pragma unroll
                for (int ni = 0; ni < 4; ni++)
                    acc[mi][ni] = __builtin_amdgcn_mfma_f32_16x16x32_bf16(
                        af[mi], bfr[ni], acc[mi][ni], 0, 0, 0);
        }
        __syncthreads();
    }

    if (MODE == 0) {
#pragma unroll
        for (int mi = 0; mi < 4; mi++) {
#pragma unroll
            for (int r = 0; r < 4; r++) {
                int row = wr + mi * 16 + (lane >> 4) * 4 + r;
                size_t rowoff = (size_t)(sbase + row) * DD;
#pragma unroll
                for (int ni = 0; ni < 4; ni++) {
                    int col = colbase + wc + ni * 16 + (lane & 15);
                    float v = acc[mi][ni][r];
                    v = v > 0.f ? v : 0.f;
                    hdst[rowoff + col] = f32_to_bf16(v);
                }
            }
        }
    } else {
#pragma unroll
        for (int mi = 0; mi < 4; mi++) {
#pragma unroll
            for (int r = 0; r < 4; r++) {
                int row = wr + mi * 16 + (lane >> 4) * 4 + r;
                int slot = sbase + row;
                if (slot < rend) { // skip padding rows
                    float w = wgt[slot];
                    size_t obase = (size_t)tok[slot] * II;
#pragma unroll
                    for (int ni = 0; ni < 4; ni++) {
                        int col = colbase + wc + ni * 16 + (lane & 15);
                        atomicAdd(&outdst[obase + col], acc[mi][ni][r] * w);
                    }
                }
            }
        }
    }
}

// ---------------- launch ----------------
extern "C" void kernel_launch(void* const* d_in, const int* in_sizes, int n_in,
                              void* d_out, int out_size, void* d_ws, size_t ws_size,
                              hipStream_t stream) {
    const float* x = (const float*)d_in[0];
    const float* weights = (const float*)d_in[1];
    const void* ens = d_in[2];
    const float* pin = (const float*)d_in[3];
    const float* pout = (const float*)d_in[4];
    float* out = (float*)d_out;

    char* ws = (char*)d_ws;
    int*   meta    = (int*)(ws);            // 1 KB
    int*   tok     = (int*)(ws + 1024);     // 20 KB
    float* wgt     = (float*)(ws + 21504);  // 20 KB   -> 41984
    u16*   x_bf    = (u16*)(ws + 41984);    // 4 MB    -> 4236288
    u16*   pin_bf  = (u16*)(ws + 4236288);  // 33.5 MB -> 37790720
    u16*   pout_bf = (u16*)(ws + 37790720); // 33.5 MB -> 71345152
    u16*   h       = (u16*)(ws + 71345152); // 21 MB   -> 92316672 total

    setup_kernel<<<dim3(1), dim3(THREADS), 0, stream>>>(ens, weights, meta, tok, wgt);

    hipMemsetAsync(d_out, 0, (size_t)out_size * sizeof(float), stream);

    convert_all<<<dim3(2048), dim3(256), 0, stream>>>(x, pin, pout, x_bf, pin_bf, pout_bf);

    gemm_kernel<0><<<dim3(MAXTILES * (DD / TN)), dim3(THREADS), 0, stream>>>(
        x_bf, pin_bf, meta, tok, wgt, h, nullptr);

    gemm_kernel<1><<<dim3(MAXTILES * (II / TN)), dim3(THREADS), 0, stream>>>(
        h, pout_bf, meta, tok, wgt, nullptr, out);
}